// Round 18
// baseline (65.386 us; speedup 1.0000x reference)
//
#include <hip/hip_runtime.h>
#include <hip/hip_bf16.h>

#define NROWS 8192
#define DDIM  512
#define NS    64
#define KK    8
#define HH    240
#define SP2   72     // samp pitch, f16 elems (64 + 8 pad)
#define ARGN  4096   // A region: 64 rows x 64 f16 (ushorts)
#define STG   8192   // stage = A | B regions (ushorts) = 16 KB

typedef __attribute__((ext_vector_type(8))) _Float16 f16x8;
typedef __attribute__((ext_vector_type(4))) _Float16 f16x4;
typedef __attribute__((ext_vector_type(4))) float f32x4;
typedef __attribute__((ext_vector_type(2))) float f32x2;

typedef __attribute__((address_space(3))) void       lds_void;
typedef const __attribute__((address_space(1))) void gbl_cvoid;

__device__ inline unsigned pk2u(float a, float b) {
    auto h = __builtin_amdgcn_cvt_pkrtz(a, b);
    unsigned u;
    __builtin_memcpy(&u, &h, sizeof(u));
    return u;
}

__device__ inline void gl16(const ushort* g, ushort* l) {
    __builtin_amdgcn_global_load_lds((gbl_cvoid*)g, (lds_void*)l, 16, 0, 0);
}

// ---------------------------------------------------------------------------
// Kernel 0: pack X, Y, Th, W1 to f16.
// ---------------------------------------------------------------------------
#define XN (NROWS * DDIM)          // 4194304
__global__ __launch_bounds__(256)
void pack_kernel(const float* __restrict__ X, const float* __restrict__ Y,
                 const float* __restrict__ Th, const float* __restrict__ W1,
                 ushort* __restrict__ Xh, ushort* __restrict__ Yh,
                 ushort* __restrict__ Thh, ushort* __restrict__ W1h)
{
    int i = (blockIdx.x * 256 + threadIdx.x) * 4;
    const float* src; ushort* dst; int off;
    if (i < XN)               { src = X;  dst = Xh;  off = i; }
    else if (i < 2 * XN)      { src = Y;  dst = Yh;  off = i - XN; }
    else if (i < 2 * XN + 262144) { src = Th; dst = Thh; off = i - 2 * XN; }
    else                      { src = W1; dst = W1h; off = i - (2 * XN + 262144); }
    float4 v = *(const float4*)(src + off);
    *(uint2*)(dst + off) = make_uint2(pk2u(v.x, v.y), pk2u(v.z, v.w));
}

// ---------------------------------------------------------------------------
// Main fused kernel (f16 operands, fp32 accumulate) — r17 + BK=64/8-step:
//  phase 1: samp64x64 = Ah @ Thh^T. BK=64 (16 MFMA/step), 8 steps (half the
//           barriers of r17), gl16 staging (zero staging VGPRs), 2-stage LDS
//           dbuf. Per step: {wait vmcnt(0); s_barrier; issue L(t+1); compute}
//           -- the waited load had a FULL step (~250cyc) in flight.
//           Both-sides XOR swizzle over 8 chunks: chunk ^= (row&7) on source
//           AND read (128B rows = 32 banks exactly, so banks depend only on
//           swizzled chunk -> conflict-free).
//  phase 2: acc (+noise) -> f16 samp LDS [64][SP2]
//  phase 3: layer-1 mfma_f32_16x16x16f16, b1 in C-init, relu + packed-W3
//           fma, fused row reductions. Unchanged from r17.
// grid = (256, 8); block = 256 (4 waves, 2x2 over 64x64). LDS 32 KB ->
// 5 blocks/CU. 64-VGPR law (r8-r16): frags reused across ks, no new regs.
// ---------------------------------------------------------------------------
__global__ __launch_bounds__(256, 4)
void proj_mlp_kernel(const ushort* __restrict__ Xh,
                     const ushort* __restrict__ Yh,
                     const float* __restrict__ Xn,
                     const ushort* __restrict__ Thh,
                     const ushort* __restrict__ W1h,
                     const float* __restrict__ b1,
                     const float* __restrict__ W3,
                     const float* __restrict__ sig_p,
                     float* __restrict__ sumx,   // [NS][128]
                     float* __restrict__ maxy,   // [NS][128]
                     float* __restrict__ sey)    // [NS][128]
{
    __shared__ __align__(16) ushort smem[2 * STG];   // 32768 B
    ushort* sl = smem;                               // samp [64][SP2] (reuse)

    const int tid  = threadIdx.x;
    const int w    = __builtin_amdgcn_readfirstlane(tid >> 6);
    const int lane = tid & 63;
    const int bx   = blockIdx.x;
    const int by   = blockIdx.y;

    const bool isX = (bx < 128);
    const int  bxl = isX ? bx : (bx - 128);
    const ushort* srcA = (isX ? Xh : Yh) + (size_t)bxl * 64 * DDIM;
    const ushort* srcB = Thh + (size_t)by * 64 * DDIM;

    // gl16 lane mapping: wave w covers local rows 16w..16w+15 via 2 calls per
    // operand (8 rows each). Source chunk XOR-swizzled by local row.
    const int r0 = (w << 4) + (lane >> 3);   // rows 16w+0..7
    const int r1 = r0 + 8;                   // rows 16w+8..15
    const int c0 = (lane & 7) ^ (r0 & 7);
    const int c1 = (lane & 7) ^ (r1 & 7);
    const ushort* gA0 = srcA + (size_t)r0 * DDIM + c0 * 8;
    const ushort* gA1 = srcA + (size_t)r1 * DDIM + c1 * 8;
    const ushort* gB0 = srcB + (size_t)r0 * DDIM + c0 * 8;
    const ushort* gB1 = srcB + (size_t)r1 * DDIM + c1 * 8;
    const int wA = w * 1024;                 // wave's A slice (2 x 512 ushorts)
    const int wB = ARGN + w * 1024;

#define ISSUE(kf, st) { const int k_ = (kf) * 64; ushort* s_ = smem + (st); \
    gl16(gA0 + k_, s_ + wA);        gl16(gA1 + k_, s_ + wA + 512); \
    gl16(gB0 + k_, s_ + wB);        gl16(gB1 + k_, s_ + wB + 512); }

    f32x4 acc[2][2];
#pragma unroll
    for (int m = 0; m < 2; ++m)
#pragma unroll
        for (int n = 0; n < 2; ++n) acc[m][n] = (f32x4){0.f, 0.f, 0.f, 0.f};

    const int wr  = (w >> 1) * 32;
    const int wc  = (w & 1) * 32;
    const int r16 = lane & 15;
    const int hi4 = lane >> 4;

    // frag offsets (ushorts): row*64 + (chunk ^ (row&7))*8, chunk = ks*4+hi4
    int offA[2][2], offB[2][2];
#pragma unroll
    for (int m = 0; m < 2; ++m) {
        int row = wr + m * 16 + r16;
#pragma unroll
        for (int ks = 0; ks < 2; ++ks)
            offA[m][ks] = row * 64 + (((ks * 4 + hi4) ^ (row & 7)) * 8);
    }
#pragma unroll
    for (int n = 0; n < 2; ++n) {
        int row = wc + n * 16 + r16;
#pragma unroll
        for (int ks = 0; ks < 2; ++ks)
            offB[n][ks] = ARGN + row * 64 + (((ks * 4 + hi4) ^ (row & 7)) * 8);
    }

    // prologue: tile 0 -> stage 0
    ISSUE(0, 0);

#pragma unroll
    for (int kt = 0; kt < 8; ++kt) {
        // L_t had a full step in flight; publish stage, then issue L_{t+1}
        asm volatile("s_waitcnt vmcnt(0)\n\ts_barrier" ::: "memory");
        if (kt < 7) ISSUE(kt + 1, ((kt + 1) & 1) * STG);

        const int cur = (kt & 1) * STG;
#pragma unroll
        for (int ks = 0; ks < 2; ++ks) {
            f16x8 af[2], bfv[2];
#pragma unroll
            for (int m = 0; m < 2; ++m) af[m]  = *(const f16x8*)(smem + cur + offA[m][ks]);
#pragma unroll
            for (int n = 0; n < 2; ++n) bfv[n] = *(const f16x8*)(smem + cur + offB[n][ks]);
#pragma unroll
            for (int m = 0; m < 2; ++m)
#pragma unroll
                for (int n = 0; n < 2; ++n)
                    acc[m][n] = __builtin_amdgcn_mfma_f32_16x16x32_f16(
                        af[m], bfv[n], acc[m][n], 0, 0, 0);
        }
    }
    __syncthreads();   // all waves done with stages before samp aliases them

    // ---- phase 2: acc (+noise) -> f16 samp LDS ------------------------------
    const float sig = *sig_p;
    const bool addnoise = (sig > 0.f) && isX;
    const int n0g = bxl * 64;

#pragma unroll
    for (int m = 0; m < 2; ++m)
#pragma unroll
        for (int n = 0; n < 2; ++n) {
            const int col  = wc + n * 16 + r16;
            const int rowb = wr + m * 16 + hi4 * 4;
            float v[4];
#pragma unroll
            for (int j = 0; j < 4; ++j) {
                v[j] = acc[m][n][j];
                if (addnoise)
                    v[j] = fmaf(sig, Xn[(size_t)(n0g + rowb + j) * (NS * KK) + by * 64 + col], v[j]);
            }
            unsigned u01 = pk2u(v[0], v[1]);
            unsigned u23 = pk2u(v[2], v[3]);
            sl[(rowb + 0) * SP2 + col] = (ushort)u01;
            sl[(rowb + 1) * SP2 + col] = (ushort)(u01 >> 16);
            sl[(rowb + 2) * SP2 + col] = (ushort)u23;
            sl[(rowb + 3) * SP2 + col] = (ushort)(u23 >> 16);
        }
    __syncthreads();

    // ---- phase 3: layer-1 16x16x16 f16 MFMA + fused reductions --------------
#pragma unroll 1
    for (int si = 0; si < 2; ++si) {
        const int sloc = w * 2 + si;
        const int s    = by * 8 + sloc;

        f16x4 bsamp[4];
#pragma unroll
        for (int nt = 0; nt < 4; ++nt) {
            f16x4 t = {0, 0, 0, 0};
            if (hi4 < 2)
                t = *(const f16x4*)(sl + (nt * 16 + r16) * SP2 + sloc * 8 + hi4 * 4);
            bsamp[nt] = t;
        }

        const ushort* w1p = W1h + (size_t)s * HH * KK;
        const float*  b1p = b1 + s * HH;
        const float*  w3p = W3 + s * HH;

        f32x2 pn2[4];
#pragma unroll
        for (int nt = 0; nt < 4; ++nt) pn2[nt] = (f32x2){0.f, 0.f};

#pragma unroll 5
        for (int ht = 0; ht < HH / 16; ++ht) {
            f16x4 aw = {0, 0, 0, 0};
            if (hi4 < 2)
                aw = *(const f16x4*)(w1p + (ht * 16 + r16) * 8 + hi4 * 4);
            float4 b4 = *(const float4*)(b1p + ht * 16 + hi4 * 4);
            float4 w4 = *(const float4*)(w3p + ht * 16 + hi4 * 4);
            f32x4 z   = (f32x4){b4.x, b4.y, b4.z, b4.w};
            f32x2 w01 = (f32x2){w4.x, w4.y};
            f32x2 w23 = (f32x2){w4.z, w4.w};
            const f32x2 zero2 = (f32x2){0.f, 0.f};
#pragma unroll
            for (int nt = 0; nt < 4; ++nt) {
                f32x4 t = __builtin_amdgcn_mfma_f32_16x16x16f16(aw, bsamp[nt], z, 0, 0, 0);
                f32x2 t01 = (f32x2){t[0], t[1]};
                f32x2 t23 = (f32x2){t[2], t[3]};
                t01 = __builtin_elementwise_max(t01, zero2);
                t23 = __builtin_elementwise_max(t23, zero2);
                pn2[nt] = __builtin_elementwise_fma(t01, w01, pn2[nt]);
                pn2[nt] = __builtin_elementwise_fma(t23, w23, pn2[nt]);
            }
        }

        if (isX) {
            float lsum = 0.f;
#pragma unroll
            for (int nt = 0; nt < 4; ++nt) lsum += pn2[nt].x + pn2[nt].y;
#pragma unroll
            for (int off = 1; off < 64; off <<= 1)
                lsum += __shfl_xor(lsum, off);
            if (lane == 0) sumx[s * 128 + bxl] = lsum;
        } else {
            float p[4];
#pragma unroll
            for (int nt = 0; nt < 4; ++nt) {
                f32x2 v = pn2[nt];
                v.x += __shfl_xor(v.x, 16);
                v.y += __shfl_xor(v.y, 16);
                v.x += __shfl_xor(v.x, 32);
                v.y += __shfl_xor(v.y, 32);
                p[nt] = v.x + v.y;
            }
            float M = fmaxf(fmaxf(p[0], p[1]), fmaxf(p[2], p[3]));
            float se = __expf(p[0] - M) + __expf(p[1] - M)
                     + __expf(p[2] - M) + __expf(p[3] - M);
#pragma unroll
            for (int off = 1; off < 16; off <<= 1) {
                float Mo = __shfl_xor(M, off);
                float so = __shfl_xor(se, off);
                float Mm = fmaxf(M, Mo);
                se = se * __expf(M - Mm) + so * __expf(Mo - Mm);
                M = Mm;
            }
            if (lane == 0) {
                maxy[s * 128 + bxl] = M;
                sey[s * 128 + bxl]  = se;
            }
        }
    }
}

// ---------------------------------------------------------------------------
// Final: 256 threads; thread (s, q) covers 32 partials; shfl-combine; wave-0
// reduces 64 slice terms -> scalar.
// ---------------------------------------------------------------------------
__global__ __launch_bounds__(256)
void final_kernel(const float* __restrict__ sumx,
                  const float* __restrict__ maxy,
                  const float* __restrict__ sey,
                  float* __restrict__ out)
{
    __shared__ float term_s[NS];
    const int tid = threadIdx.x;
    const int s = tid >> 2, q = tid & 3;
    const int base = s * 128 + q * 32;

    float sum = 0.f, M = -3.4e38f;
#pragma unroll 8
    for (int i = 0; i < 32; ++i) {
        sum += sumx[base + i];
        M = fmaxf(M, maxy[base + i]);
    }
    float se = 0.f;
#pragma unroll 8
    for (int i = 0; i < 32; ++i)
        se += sey[base + i] * __expf(maxy[base + i] - M);

#pragma unroll
    for (int off = 1; off < 4; off <<= 1) {
        float Mo = __shfl_xor(M, off);
        float so = __shfl_xor(se, off);
        float su = __shfl_xor(sum, off);
        float Mm = fmaxf(M, Mo);
        se = se * __expf(M - Mm) + so * __expf(Mo - Mm);
        M = Mm;
        sum += su;
    }
    if (q == 0)
        term_s[s] = M + logf(se) - logf((float)NROWS) - sum * (1.0f / (float)NROWS);
    __syncthreads();
    if (tid < 64) {
        float v = term_s[tid];
#pragma unroll
        for (int off = 1; off < 64; off <<= 1) v += __shfl_xor(v, off);
        if (tid == 0) out[0] = v * (1.0f / (float)NS);
    }
}

// ---------------------------------------------------------------------------
extern "C" void kernel_launch(void* const* d_in, const int* in_sizes, int n_in,
                              void* d_out, int out_size, void* d_ws, size_t ws_size,
                              hipStream_t stream)
{
    const float* X   = (const float*)d_in[0];
    const float* Y   = (const float*)d_in[1];
    const float* Xn  = (const float*)d_in[2];
    const float* Th  = (const float*)d_in[3];
    const float* W1  = (const float*)d_in[4];
    const float* b1  = (const float*)d_in[5];
    const float* W3  = (const float*)d_in[6];
    // d_in[7] = b3: cancels exactly between mean_x and LSE_y -> unused
    const float* sig = (const float*)d_in[8];

    ushort* Xh   = (ushort*)d_ws;                     // 4,194,304 f16
    ushort* Yh   = Xh + XN;                           // 4,194,304 f16
    ushort* Thh  = Yh + XN;                           // 262,144 f16
    ushort* W1h  = Thh + 262144;                      // 122,880 f16
    float*  sumx = (float*)(W1h + 122880);
    float*  maxy = sumx + NS * 128;
    float*  sey  = maxy + NS * 128;

    pack_kernel<<<(2 * XN + 262144 + 122880) / 1024, 256, 0, stream>>>(
        X, Y, Th, W1, Xh, Yh, Thh, W1h);

    dim3 g1(256, 8, 1);
    proj_mlp_kernel<<<g1, 256, 0, stream>>>(Xh, Yh, Xn, Thh, W1h, b1, W3,
                                            sig, sumx, maxy, sey);
    final_kernel<<<1, 256, 0, stream>>>(sumx, maxy, sey, (float*)d_out);
}